// Round 1
// baseline (510.613 us; speedup 1.0000x reference)
//
#include <hip/hip_runtime.h>
#include <stdint.h>

#define TOKENS 16384
#define D_IN   4096
#define D_OUT  4096

typedef int v4i __attribute__((ext_vector_type(4)));

__device__ __forceinline__ void gl_lds16(const void* g, void* l) {
    __builtin_amdgcn_global_load_lds(
        (const __attribute__((address_space(1))) void*)g,
        (__attribute__((address_space(3))) void*)l, 16, 0, 0);
}

// Pack x -> int8 signs, fused abs-sum reduction.
__global__ void pack_x_abssum(const float* __restrict__ x,
                              signed char* __restrict__ xs,
                              float* __restrict__ sum_out, int n4) {
    int i = blockIdx.x * blockDim.x + threadIdx.x;
    const int stride = gridDim.x * blockDim.x;
    float acc = 0.f;
    const float4* x4 = (const float4*)x;
    char4* xs4 = (char4*)xs;
    for (; i < n4; i += stride) {
        float4 v = x4[i];
        char4 s;
        s.x = (signed char)((v.x > 0.f) - (v.x < 0.f));
        s.y = (signed char)((v.y > 0.f) - (v.y < 0.f));
        s.z = (signed char)((v.z > 0.f) - (v.z < 0.f));
        s.w = (signed char)((v.w > 0.f) - (v.w < 0.f));
        xs4[i] = s;
        acc += fabsf(v.x) + fabsf(v.y) + fabsf(v.z) + fabsf(v.w);
    }
#pragma unroll
    for (int o = 32; o > 0; o >>= 1) acc += __shfl_down(acc, o);
    if ((threadIdx.x & 63) == 0) atomicAdd(sum_out, acc);
}

__global__ void pack_w_kernel(const float* __restrict__ w,
                              signed char* __restrict__ ws, int n4) {
    int i = blockIdx.x * blockDim.x + threadIdx.x;
    const int stride = gridDim.x * blockDim.x;
    const float4* w4 = (const float4*)w;
    char4* ws4 = (char4*)ws;
    for (; i < n4; i += stride) {
        float4 v = w4[i];
        char4 s;
        s.x = (signed char)((v.x > 0.f) - (v.x < 0.f));
        s.y = (signed char)((v.y > 0.f) - (v.y < 0.f));
        s.z = (signed char)((v.z > 0.f) - (v.z < 0.f));
        s.w = (signed char)((v.w > 0.f) - (v.w < 0.f));
        ws4[i] = s;
    }
}

// C = A (M x K, i8 signs) * B^T (B is N x K, i8 signs), epilogue (acc+bias)*scale.
// 128x128 tile, BK=64, 4 waves (2x2), mfma_i32_16x16x64_i8. m97-style 2-barrier loop.
__global__ __launch_bounds__(256, 2) void bin_gemm(
    const signed char* __restrict__ A,
    const signed char* __restrict__ B,
    const float* __restrict__ bias,
    const float* __restrict__ sum_ptr,
    float* __restrict__ out) {
    __shared__ signed char As[128 * 64];  // 8 KB
    __shared__ signed char Bs[128 * 64];  // 8 KB

    const int t    = threadIdx.x;
    const int lane = t & 63;
    const int wid  = t >> 6;
    const int wm   = wid >> 1;   // 0..1
    const int wn   = wid & 1;    // 0..1
    const int bn   = blockIdx.x & 31;   // N / 128 = 32
    const int bm   = blockIdx.x >> 5;   // M / 128 = 128

    const long K = D_IN;
    // staging: thread t loads 16B at row (t>>2), chunk (t&3); two row-groups (p=0,1)
    const signed char* ga = A + (long)(bm * 128 + (t >> 2)) * K + (t & 3) * 16;
    const signed char* gb = B + (long)(bn * 128 + (t >> 2)) * K + (t & 3) * 16;
    signed char* lA = &As[t * 16];
    signed char* lB = &Bs[t * 16];

    v4i acc[4][4];
#pragma unroll
    for (int i = 0; i < 4; i++)
#pragma unroll
        for (int j = 0; j < 4; j++) acc[i][j] = (v4i){0, 0, 0, 0};

    const int arow = lane & 15;
    const int kb   = (lane >> 4) * 16;

    for (int kt = 0; kt < D_IN; kt += 64) {
        gl_lds16(ga + kt,            lA);
        gl_lds16(ga + 64 * K + kt,   lA + 4096);
        gl_lds16(gb + kt,            lB);
        gl_lds16(gb + 64 * K + kt,   lB + 4096);
        asm volatile("s_waitcnt vmcnt(0)" ::: "memory");
        __syncthreads();

        v4i af[4], bf[4];
#pragma unroll
        for (int ai = 0; ai < 4; ai++)
            af[ai] = *(const v4i*)&As[(wm * 64 + ai * 16 + arow) * 64 + kb];
#pragma unroll
        for (int bj = 0; bj < 4; bj++)
            bf[bj] = *(const v4i*)&Bs[(wn * 64 + bj * 16 + arow) * 64 + kb];
#pragma unroll
        for (int ai = 0; ai < 4; ai++)
#pragma unroll
            for (int bj = 0; bj < 4; bj++)
                acc[ai][bj] = __builtin_amdgcn_mfma_i32_16x16x64_i8(
                    af[ai], bf[bj], acc[ai][bj], 0, 0, 0);
        __syncthreads();
    }

    const float scale = *sum_ptr * (1.0f / 67108864.0f);
#pragma unroll
    for (int bj = 0; bj < 4; bj++) {
        const int col = bn * 128 + wn * 64 + bj * 16 + (lane & 15);
        const float bb = bias[col];
#pragma unroll
        for (int ai = 0; ai < 4; ai++) {
            const int row0 = bm * 128 + wm * 64 + ai * 16 + (lane >> 4) * 4;
#pragma unroll
            for (int r = 0; r < 4; r++) {
                out[(long)(row0 + r) * D_OUT + col] =
                    ((float)acc[ai][bj][r] + bb) * scale;
            }
        }
    }
}

extern "C" void kernel_launch(void* const* d_in, const int* in_sizes, int n_in,
                              void* d_out, int out_size, void* d_ws, size_t ws_size,
                              hipStream_t stream) {
    const float* x = (const float*)d_in[0];
    const float* W = (const float*)d_in[1];
    const float* b = (const float*)d_in[2];
    float* out = (float*)d_out;

    float* sum_ptr   = (float*)d_ws;
    signed char* xs  = (signed char*)d_ws + 256;
    signed char* wsg = xs + (size_t)TOKENS * D_IN;   // +64 MB

    hipMemsetAsync(d_ws, 0, 256, stream);
    pack_x_abssum<<<2048, 256, 0, stream>>>(x, xs, sum_ptr, TOKENS * D_IN / 4);
    pack_w_kernel<<<1024, 256, 0, stream>>>(W, wsg, D_OUT * D_IN / 4);
    bin_gemm<<<(TOKENS / 128) * (D_OUT / 128), 256, 0, stream>>>(xs, wsg, b, sum_ptr, out);
}

// Round 2
// 497.510 us; speedup vs baseline: 1.0263x; 1.0263x over previous
//
#include <hip/hip_runtime.h>
#include <stdint.h>

#define TOKENS 16384
#define D_IN   4096
#define D_OUT  4096
#define NKT    32   // K-tiles of 128 i8

typedef int v4i __attribute__((ext_vector_type(4)));

__device__ __forceinline__ void gl_lds16(const void* g, void* l) {
    __builtin_amdgcn_global_load_lds(
        (const __attribute__((address_space(1))) void*)g,
        (__attribute__((address_space(3))) void*)l, 16, 0, 0);
}

#define BARRIER() __builtin_amdgcn_s_barrier()
#define LGKM0()  do { asm volatile("s_waitcnt lgkmcnt(0)" ::: "memory"); \
                      __builtin_amdgcn_sched_barrier(0); } while (0)
#define WAIT_VM4() asm volatile("s_waitcnt vmcnt(4)" ::: "memory")
#define WAIT_VM0() asm volatile("s_waitcnt vmcnt(0)" ::: "memory")

// ---------------------------------------------------------------------------
// Packing: tile image layout. For tile (mt|nt, kt, h): 1024 slots of 16B,
// slot s = ch*128 + r  <->  signs[row = *t*256 + h*128 + r][k = kt*128 + ch*16 .. +16]
// This IS the LDS image: staging is linear both sides; ds_read_b128 is
// bank-conflict-free (lane-octet start banks cover 0,4,...,28).
// ---------------------------------------------------------------------------

__global__ __launch_bounds__(256) void pack_x_abssum(
        const float* __restrict__ x, signed char* __restrict__ xp,
        float* __restrict__ sum_out) {
    const int b  = blockIdx.x;          // 64*32*2 = 4096 blocks
    const int mt = b >> 6;
    const int kt = (b >> 1) & 31;
    const int h  = b & 1;
    const int t  = threadIdx.x;
    const int j  = t & 3;               // float4 within 16-float slot
    const int g  = t >> 2;              // slot group 0..63
    const float* src = x + ((size_t)(mt * 256 + h * 128)) * D_IN + kt * 128;
    char4* dst = (char4*)(xp + (((size_t)mt * 32 + kt) * 2 + h) * 16384);
    float accum = 0.f;
#pragma unroll
    for (int p = 0; p < 16; ++p) {
        const int s  = p * 64 + g;      // slot 0..1023
        const int r  = s & 127;
        const int ch = s >> 7;
        float4 v = *(const float4*)(src + (size_t)r * D_IN + ch * 16 + j * 4);
        char4 c;
        c.x = (signed char)((v.x > 0.f) - (v.x < 0.f));
        c.y = (signed char)((v.y > 0.f) - (v.y < 0.f));
        c.z = (signed char)((v.z > 0.f) - (v.z < 0.f));
        c.w = (signed char)((v.w > 0.f) - (v.w < 0.f));
        dst[p * 256 + t] = c;           // == s*4 + j : fully coalesced
        accum += fabsf(v.x) + fabsf(v.y) + fabsf(v.z) + fabsf(v.w);
    }
#pragma unroll
    for (int o = 32; o > 0; o >>= 1) accum += __shfl_down(accum, o);
    if ((t & 63) == 0) atomicAdd(sum_out, accum);
}

__global__ __launch_bounds__(256) void pack_w_kernel(
        const float* __restrict__ w, signed char* __restrict__ wp) {
    const int b  = blockIdx.x;          // 16*32*2 = 1024 blocks
    const int nt = b >> 6;
    const int kt = (b >> 1) & 31;
    const int h  = b & 1;
    const int t  = threadIdx.x;
    const int j  = t & 3;
    const int g  = t >> 2;
    const float* src = w + ((size_t)(nt * 256 + h * 128)) * D_IN + kt * 128;
    char4* dst = (char4*)(wp + (((size_t)nt * 32 + kt) * 2 + h) * 16384);
#pragma unroll
    for (int p = 0; p < 16; ++p) {
        const int s  = p * 64 + g;
        const int r  = s & 127;
        const int ch = s >> 7;
        float4 v = *(const float4*)(src + (size_t)r * D_IN + ch * 16 + j * 4);
        char4 c;
        c.x = (signed char)((v.x > 0.f) - (v.x < 0.f));
        c.y = (signed char)((v.y > 0.f) - (v.y < 0.f));
        c.z = (signed char)((v.z > 0.f) - (v.z < 0.f));
        c.w = (signed char)((v.w > 0.f) - (v.w < 0.f));
        dst[p * 256 + t] = c;
    }
}

// ---------------------------------------------------------------------------
// 256x256 tile, BK=128, 8 waves (2M x 4N), 4 phases/K-tile, counted vmcnt(4).
// LDS: 2 dbuf x {A0,A1,B0,B1} x 16KB = 128 KB.  1 block/CU.
// Phase q0/q1 split: P0/P1 consume only kk=0 chunks (first 8KB of each half),
// P2/P3 consume kk=1. Stage order per tile t (for t+1): Aq0,Bq0,Aq1,Bq1 ->
// two vmcnt(4) waits per K-tile, 4 loads always in flight.
// ---------------------------------------------------------------------------

#define STG_A(d, kt, h, q) gl_lds16(aS + (size_t)(kt) * 32768 + (h) * 16384 + (q) * 8192, \
                                    (signed char*)&lds[d][h][(q) * 512] + t * 16)
#define STG_B(d, kt, h, q) gl_lds16(bS + (size_t)(kt) * 32768 + (h) * 16384 + (q) * 8192, \
                                    (signed char*)&lds[d][2 + (h)][(q) * 512] + t * 16)

__global__ __launch_bounds__(512, 2) void bin_gemm(
    const signed char* __restrict__ Ap, const signed char* __restrict__ Bp,
    const float* __restrict__ bias, const float* __restrict__ sum_ptr,
    float* __restrict__ out) {
    __shared__ v4i lds[2][4][1024];     // 128 KB

    const int t    = threadIdx.x;       // 0..511
    const int lane = t & 63;
    const int wid  = t >> 6;            // 0..7
    const int wm   = wid >> 2;          // M half (0/1)
    const int wn   = wid & 3;           // N quarter (0..3)
    const int lrow = lane & 15;
    const int lch  = lane >> 4;

    // XCD-aware bijective swizzle (nwg=1024, 1024%8==0)
    const int bid = blockIdx.x;
    const int swz = (bid & 7) * 128 + (bid >> 3);
    const int bn  = swz & 15;           // 16 N-blocks of 256
    const int bm  = swz >> 4;           // 64 M-blocks of 256

    const signed char* aS = Ap + (size_t)bm * (32 * 32768) + (size_t)t * 16;
    const signed char* bS = Bp + (size_t)bn * (32 * 32768) + (size_t)t * 16;

    v4i acc[8][4];
#pragma unroll
    for (int i = 0; i < 8; ++i)
#pragma unroll
        for (int j = 0; j < 4; ++j) acc[i][j] = (v4i){0, 0, 0, 0};

    // prologue: stage tile 0 into dbuf 0 in deadline order
    STG_A(0, 0, 0, 0); STG_A(0, 0, 1, 0); STG_B(0, 0, 0, 0); STG_B(0, 0, 1, 0);
    STG_A(0, 0, 0, 1); STG_A(0, 0, 1, 1); STG_B(0, 0, 0, 1); STG_B(0, 0, 1, 1);
    WAIT_VM4();      // q0 halves landed; q1 (4 loads) in flight
    BARRIER();

    int d = 0;
    for (int ktile = 0; ktile < NKT; ++ktile) {
        const bool nx = ktile < NKT - 1;
        const v4i* LA = &lds[d][wm][0];
        const v4i* LB = &lds[d][2 + (wn >> 1)][0];
        const int bcol = (wn & 1) * 64;
        v4i af[4], bf[4];

        // ---- P0: fr0-3 x fn0-3, kk=0 (q0 data) ----
#pragma unroll
        for (int fr = 0; fr < 4; ++fr) af[fr] = LA[lch * 128 + fr * 16 + lrow];
#pragma unroll
        for (int fn = 0; fn < 4; ++fn) bf[fn] = LB[lch * 128 + bcol + fn * 16 + lrow];
        if (nx) { STG_A(d ^ 1, ktile + 1, 0, 0); STG_A(d ^ 1, ktile + 1, 1, 0); }
        BARRIER(); LGKM0();
        __builtin_amdgcn_s_setprio(1);
#pragma unroll
        for (int fr = 0; fr < 4; ++fr)
#pragma unroll
            for (int fn = 0; fn < 4; ++fn)
                acc[fr][fn] = __builtin_amdgcn_mfma_i32_16x16x64_i8(af[fr], bf[fn], acc[fr][fn], 0, 0, 0);
        __builtin_amdgcn_s_setprio(0);
        BARRIER();

        // ---- P1: fr4-7 x fn0-3, kk=0 ----
#pragma unroll
        for (int fr = 0; fr < 4; ++fr) af[fr] = LA[lch * 128 + (4 + fr) * 16 + lrow];
        if (nx) { STG_B(d ^ 1, ktile + 1, 0, 0); STG_B(d ^ 1, ktile + 1, 1, 0); }
        BARRIER(); LGKM0();
        __builtin_amdgcn_s_setprio(1);
#pragma unroll
        for (int fr = 0; fr < 4; ++fr)
#pragma unroll
            for (int fn = 0; fn < 4; ++fn)
                acc[4 + fr][fn] = __builtin_amdgcn_mfma_i32_16x16x64_i8(af[fr], bf[fn], acc[4 + fr][fn], 0, 0, 0);
        __builtin_amdgcn_s_setprio(0);
        if (nx) { WAIT_VM4(); } else { WAIT_VM0(); }   // next-phase reads q1
        BARRIER();

        // ---- P2: fr0-3 x fn0-3, kk=1 (q1 data) ----
#pragma unroll
        for (int fr = 0; fr < 4; ++fr) af[fr] = LA[(4 + lch) * 128 + fr * 16 + lrow];
#pragma unroll
        for (int fn = 0; fn < 4; ++fn) bf[fn] = LB[(4 + lch) * 128 + bcol + fn * 16 + lrow];
        if (nx) { STG_A(d ^ 1, ktile + 1, 0, 1); STG_A(d ^ 1, ktile + 1, 1, 1); }
        BARRIER(); LGKM0();
        __builtin_amdgcn_s_setprio(1);
#pragma unroll
        for (int fr = 0; fr < 4; ++fr)
#pragma unroll
            for (int fn = 0; fn < 4; ++fn)
                acc[fr][fn] = __builtin_amdgcn_mfma_i32_16x16x64_i8(af[fr], bf[fn], acc[fr][fn], 0, 0, 0);
        __builtin_amdgcn_s_setprio(0);
        BARRIER();

        // ---- P3: fr4-7 x fn0-3, kk=1 ----
#pragma unroll
        for (int fr = 0; fr < 4; ++fr) af[fr] = LA[(4 + lch) * 128 + (4 + fr) * 16 + lrow];
        if (nx) { STG_B(d ^ 1, ktile + 1, 0, 1); STG_B(d ^ 1, ktile + 1, 1, 1); }
        BARRIER(); LGKM0();
        __builtin_amdgcn_s_setprio(1);
#pragma unroll
        for (int fr = 0; fr < 4; ++fr)
#pragma unroll
            for (int fn = 0; fn < 4; ++fn)
                acc[4 + fr][fn] = __builtin_amdgcn_mfma_i32_16x16x64_i8(af[fr], bf[fn], acc[4 + fr][fn], 0, 0, 0);
        __builtin_amdgcn_s_setprio(0);
        if (nx) { WAIT_VM4(); }        // next tile's P0 reads its q0
        BARRIER();

        d ^= 1;
    }

    // epilogue: out = (acc + bias) * scale
    const float scale = *sum_ptr * (1.0f / 67108864.0f);
#pragma unroll
    for (int fn = 0; fn < 4; ++fn) {
        const int col = bn * 256 + wn * 64 + fn * 16 + lrow;
        const float bb = bias[col];
#pragma unroll
        for (int fg = 0; fg < 8; ++fg) {
            const int row0 = bm * 256 + wm * 128 + fg * 16 + lch * 4;
#pragma unroll
            for (int ri = 0; ri < 4; ++ri)
                out[(size_t)(row0 + ri) * D_OUT + col] =
                    ((float)acc[fg][fn][ri] + bb) * scale;
        }
    }
}

extern "C" void kernel_launch(void* const* d_in, const int* in_sizes, int n_in,
                              void* d_out, int out_size, void* d_ws, size_t ws_size,
                              hipStream_t stream) {
    const float* x = (const float*)d_in[0];
    const float* W = (const float*)d_in[1];
    const float* b = (const float*)d_in[2];
    float* out = (float*)d_out;

    float* sum_ptr  = (float*)d_ws;
    signed char* xs = (signed char*)d_ws + 256;
    signed char* wp = xs + (size_t)TOKENS * D_IN;   // +64 MB

    hipMemsetAsync(d_ws, 0, 256, stream);
    pack_x_abssum<<<64 * 32 * 2, 256, 0, stream>>>(x, xs, sum_ptr);
    pack_w_kernel<<<16 * 32 * 2, 256, 0, stream>>>(W, wp);
    bin_gemm<<<1024, 512, 0, stream>>>(xs, wp, b, sum_ptr, out);
}